// Round 1
// baseline (3448.724 us; speedup 1.0000x reference)
//
#include <hip/hip_runtime.h>

static constexpr int F = 128;   // feature width of x / hidden layers

// ---------------- degree: one fp32 atomic per edge ----------------
__global__ __launch_bounds__(256) void deg_kernel(const int* __restrict__ dst,
                                                  float* __restrict__ deg, int nE) {
    int i = blockIdx.x * blockDim.x + threadIdx.x;
    if (i < nE) atomicAdd(&deg[dst[i]], 1.0f);
}

// ---------------- scatter: neigh[dst] += x[src], 32 lanes per edge ----------------
__global__ __launch_bounds__(256) void scatter_kernel(const float* __restrict__ x,
                                                      const int* __restrict__ src,
                                                      const int* __restrict__ dst,
                                                      float* __restrict__ neigh, int nE) {
    int idx = blockIdx.x * blockDim.x + threadIdx.x;
    int e = idx >> 5;                 // 32 threads per edge
    if (e >= nE) return;
    int q = (idx & 31) << 2;          // 4 floats per thread -> 128 floats per edge
    int s = src[e];                   // broadcast load (same addr across 32 lanes)
    int d = dst[e];
    const float4 v = *reinterpret_cast<const float4*>(x + (size_t)s * F + q);
    float* p = neigh + (size_t)d * F + q;
    atomicAdd(p + 0, v.x);
    atomicAdd(p + 1, v.y);
    atomicAdd(p + 2, v.z);
    atomicAdd(p + 3, v.w);
}

// ---------------- fused SAGE layer GEMM ----------------
// out[r] = act( x[r] @ Wself + (neigh[r]/max(deg[r],1)) @ Wneigh + b )
// 256 threads/block, 64 rows/block, thread micro-tile = RPT rows x 4 cols.
// LDS: As (x rows) + An (pre-scaled neigh rows) = exactly 64 KB.
template<int OUTF, bool RELU>
__global__ __launch_bounds__(256) void sage_gemm(const float* xin,
                                                 const float* __restrict__ neigh,
                                                 const float* __restrict__ deg,
                                                 const float* __restrict__ wself,
                                                 const float* __restrict__ wneigh,
                                                 const float* __restrict__ bias,
                                                 float* out, int nRows)
{
    constexpr int MT  = 64;            // rows per block
    constexpr int CG  = OUTF / 4;      // col groups of 4
    constexpr int RPT = MT * CG / 256; // rows per thread (128->8, 64->4)
    __shared__ float As[MT][F];
    __shared__ float An[MT][F];

    const int tid  = threadIdx.x;
    const int row0 = blockIdx.x * MT;

    // ---- stage 64 rows of x and deg-scaled neigh into LDS (coalesced float4) ----
    for (int i = tid; i < MT * (F / 4); i += 256) {
        int r   = i >> 5;
        int c4  = (i & 31) << 2;
        int g   = row0 + r;
        float4 vx = make_float4(0.f, 0.f, 0.f, 0.f);
        float4 vn = make_float4(0.f, 0.f, 0.f, 0.f);
        float inv = 0.f;
        if (g < nRows) {
            vx  = *reinterpret_cast<const float4*>(xin   + (size_t)g * F + c4);
            vn  = *reinterpret_cast<const float4*>(neigh + (size_t)g * F + c4);
            inv = 1.0f / fmaxf(deg[g], 1.0f);
        }
        As[r][c4]     = vx.x;       As[r][c4 + 1] = vx.y;
        As[r][c4 + 2] = vx.z;       As[r][c4 + 3] = vx.w;
        An[r][c4]     = vn.x * inv; An[r][c4 + 1] = vn.y * inv;
        An[r][c4 + 2] = vn.z * inv; An[r][c4 + 3] = vn.w * inv;
    }
    __syncthreads();

    const int cg = tid % CG;
    const int rg = tid / CG;
    const int c  = cg * 4;
    const int rb = rg * RPT;

    float acc[RPT][4];
#pragma unroll
    for (int r = 0; r < RPT; ++r)
        acc[r][0] = acc[r][1] = acc[r][2] = acc[r][3] = 0.f;

#pragma unroll 4
    for (int k = 0; k < F; ++k) {
        const float4 wsv = *reinterpret_cast<const float4*>(wself  + k * OUTF + c);
        const float4 wnv = *reinterpret_cast<const float4*>(wneigh + k * OUTF + c);
#pragma unroll
        for (int r = 0; r < RPT; ++r) {
            float ax = As[rb + r][k];
            float an = An[rb + r][k];
            acc[r][0] = fmaf(ax, wsv.x, fmaf(an, wnv.x, acc[r][0]));
            acc[r][1] = fmaf(ax, wsv.y, fmaf(an, wnv.y, acc[r][1]));
            acc[r][2] = fmaf(ax, wsv.z, fmaf(an, wnv.z, acc[r][2]));
            acc[r][3] = fmaf(ax, wsv.w, fmaf(an, wnv.w, acc[r][3]));
        }
    }

    const float4 bv = *reinterpret_cast<const float4*>(bias + c);
#pragma unroll
    for (int r = 0; r < RPT; ++r) {
        int g = row0 + rb + r;
        if (g >= nRows) continue;
        float4 o;
        o.x = acc[r][0] + bv.x;
        o.y = acc[r][1] + bv.y;
        o.z = acc[r][2] + bv.z;
        o.w = acc[r][3] + bv.w;
        if (RELU) {
            o.x = fmaxf(o.x, 0.f); o.y = fmaxf(o.y, 0.f);
            o.z = fmaxf(o.z, 0.f); o.w = fmaxf(o.w, 0.f);
        }
        *reinterpret_cast<float4*>(out + (size_t)g * OUTF + c) = o;
    }
}

extern "C" void kernel_launch(void* const* d_in, const int* in_sizes, int n_in,
                              void* d_out, int out_size, void* d_ws, size_t ws_size,
                              hipStream_t stream) {
    const float* x   = (const float*)d_in[0];
    const int*   src = (const int*)  d_in[1];
    const int*   dst = (const int*)  d_in[2];
    const float* ws1 = (const float*)d_in[3];
    const float* wn1 = (const float*)d_in[4];
    const float* b1  = (const float*)d_in[5];
    const float* ws2 = (const float*)d_in[6];
    const float* wn2 = (const float*)d_in[7];
    const float* b2  = (const float*)d_in[8];
    const float* ws3 = (const float*)d_in[9];
    const float* wn3 = (const float*)d_in[10];
    const float* b3  = (const float*)d_in[11];
    float* out = (float*)d_out;

    const int N = in_sizes[0] / F;   // 50000
    const int E = in_sizes[1];       // 640000

    // ---- workspace layout: deg | neigh (scatter accum) | h (hidden, reused in place) ----
    char* w = (char*)d_ws;
    const size_t degBytes  = ((size_t)N * 4 + 511) & ~(size_t)511;
    const size_t featBytes = (size_t)N * F * 4;
    float* deg   = (float*)(w);
    float* neigh = (float*)(w + degBytes);
    float* h     = (float*)(w + degBytes + featBytes);

    const dim3 blk(256);
    const int degGrid  = (E + 255) / 256;
    const int scatGrid = (int)(((size_t)E * 32 + 255) / 256);
    const int gemmGrid = (N + 63) / 64;

    // degrees (graph is identical for all 3 layers)
    hipMemsetAsync(deg, 0, (size_t)N * 4, stream);
    deg_kernel<<<degGrid, blk, 0, stream>>>(dst, deg, E);

    // ---- layer 1: x -> h ----
    hipMemsetAsync(neigh, 0, featBytes, stream);
    scatter_kernel<<<scatGrid, blk, 0, stream>>>(x, src, dst, neigh, E);
    sage_gemm<128, true><<<gemmGrid, blk, 0, stream>>>(x, neigh, deg, ws1, wn1, b1, h, N);

    // ---- layer 2: h -> h (in place: each block stages its rows into LDS before writing) ----
    hipMemsetAsync(neigh, 0, featBytes, stream);
    scatter_kernel<<<scatGrid, blk, 0, stream>>>(h, src, dst, neigh, E);
    sage_gemm<128, true><<<gemmGrid, blk, 0, stream>>>(h, neigh, deg, ws2, wn2, b2, h, N);

    // ---- layer 3: h -> out (64 cols, no relu) ----
    hipMemsetAsync(neigh, 0, featBytes, stream);
    scatter_kernel<<<scatGrid, blk, 0, stream>>>(h, src, dst, neigh, E);
    sage_gemm<64, false><<<gemmGrid, blk, 0, stream>>>(h, neigh, deg, ws3, wn3, b3, out, N);
}

// Round 2
// 450.571 us; speedup vs baseline: 7.6541x; 7.6541x over previous
//
#include <hip/hip_runtime.h>

static constexpr int F = 128;   // feature width of x / hidden layers

// ---------------- CSR build step 1: int histogram of dst ----------------
__global__ __launch_bounds__(256) void hist_kernel(const int* __restrict__ dst,
                                                   int* __restrict__ cnt, int nE) {
    int i = blockIdx.x * blockDim.x + threadIdx.x;
    if (i < nE) atomicAdd(&cnt[dst[i]], 1);
}

// ---------------- CSR build step 2: exclusive scan (single 1024-thread block) ----------------
__global__ __launch_bounds__(1024) void scan_kernel(const int* __restrict__ cnt,
                                                    int* __restrict__ rowptr, int n) {
    __shared__ int buf[1024];
    __shared__ int carry;
    const int tid = threadIdx.x;
    if (tid == 0) { carry = 0; rowptr[0] = 0; }
    __syncthreads();
    for (int base = 0; base < n; base += 1024) {
        int v = (base + tid < n) ? cnt[base + tid] : 0;
        buf[tid] = v;
        __syncthreads();
        for (int off = 1; off < 1024; off <<= 1) {
            int t = (tid >= off) ? buf[tid - off] : 0;
            __syncthreads();
            buf[tid] += t;
            __syncthreads();
        }
        int incl = buf[tid] + carry;          // inclusive prefix incl. carry
        if (base + tid < n) rowptr[base + tid + 1] = incl;
        __syncthreads();
        if (tid == 1023) carry = incl;        // chunk total folded in
        __syncthreads();
    }
}

// ---------------- CSR build step 3: bucket-fill src indices ----------------
__global__ __launch_bounds__(256) void fill_kernel(const int* __restrict__ src,
                                                   const int* __restrict__ dst,
                                                   const int* __restrict__ rowptr,
                                                   int* __restrict__ fillcnt,
                                                   int* __restrict__ col, int nE) {
    int e = blockIdx.x * blockDim.x + threadIdx.x;
    if (e < nE) {
        int d = dst[e];
        int pos = atomicAdd(&fillcnt[d], 1);
        col[rowptr[d] + pos] = src[e];
    }
}

// ---------------- gather: neigh[v] = mean_{u in N(v)} x[u]  (no atomics) ----------------
// 32 lanes per node, float4 per lane, 4-way unrolled neighbor loop for MLP.
__global__ __launch_bounds__(256) void gather_kernel(const float* __restrict__ x,
                                                     const int* __restrict__ rowptr,
                                                     const int* __restrict__ col,
                                                     float* __restrict__ neigh, int nNodes) {
    const int grp  = (blockIdx.x * blockDim.x + threadIdx.x) >> 5;
    const int lane = threadIdx.x & 31;
    if (grp >= nNodes) return;
    const int beg = rowptr[grp];
    const int end = rowptr[grp + 1];
    const int q   = lane << 2;

    float4 a0 = make_float4(0.f, 0.f, 0.f, 0.f);
    float4 a1 = make_float4(0.f, 0.f, 0.f, 0.f);
    float4 a2 = make_float4(0.f, 0.f, 0.f, 0.f);
    float4 a3 = make_float4(0.f, 0.f, 0.f, 0.f);

    int j = beg;
    for (; j + 3 < end; j += 4) {
        const int u0 = col[j], u1 = col[j + 1], u2 = col[j + 2], u3 = col[j + 3];
        const float4 v0 = *reinterpret_cast<const float4*>(x + (size_t)u0 * F + q);
        const float4 v1 = *reinterpret_cast<const float4*>(x + (size_t)u1 * F + q);
        const float4 v2 = *reinterpret_cast<const float4*>(x + (size_t)u2 * F + q);
        const float4 v3 = *reinterpret_cast<const float4*>(x + (size_t)u3 * F + q);
        a0.x += v0.x; a0.y += v0.y; a0.z += v0.z; a0.w += v0.w;
        a1.x += v1.x; a1.y += v1.y; a1.z += v1.z; a1.w += v1.w;
        a2.x += v2.x; a2.y += v2.y; a2.z += v2.z; a2.w += v2.w;
        a3.x += v3.x; a3.y += v3.y; a3.z += v3.z; a3.w += v3.w;
    }
    for (; j < end; ++j) {
        const int u = col[j];
        const float4 v = *reinterpret_cast<const float4*>(x + (size_t)u * F + q);
        a0.x += v.x; a0.y += v.y; a0.z += v.z; a0.w += v.w;
    }

    const int deg = end - beg;
    const float inv = 1.0f / (float)(deg > 1 ? deg : 1);
    float4 o;
    o.x = (a0.x + a1.x + a2.x + a3.x) * inv;
    o.y = (a0.y + a1.y + a2.y + a3.y) * inv;
    o.z = (a0.z + a1.z + a2.z + a3.z) * inv;
    o.w = (a0.w + a1.w + a2.w + a3.w) * inv;
    *reinterpret_cast<float4*>(neigh + (size_t)grp * F + q) = o;
}

// ---------------- fused SAGE layer GEMM ----------------
// out[r] = act( x[r] @ Wself + neigh[r] @ Wneigh + b )   (neigh pre-scaled by 1/deg)
// 256 threads/block, 64 rows/block, thread micro-tile = RPT rows x 4 cols.
template<int OUTF, bool RELU>
__global__ __launch_bounds__(256) void sage_gemm(const float* xin,
                                                 const float* __restrict__ neigh,
                                                 const float* __restrict__ wself,
                                                 const float* __restrict__ wneigh,
                                                 const float* __restrict__ bias,
                                                 float* out, int nRows)
{
    constexpr int MT  = 64;            // rows per block
    constexpr int CG  = OUTF / 4;      // col groups of 4
    constexpr int RPT = MT * CG / 256; // rows per thread (128->8, 64->4)
    __shared__ float As[MT][F];
    __shared__ float An[MT][F];

    const int tid  = threadIdx.x;
    const int row0 = blockIdx.x * MT;

    // ---- stage 64 rows of x and neigh into LDS (coalesced float4) ----
    for (int i = tid; i < MT * (F / 4); i += 256) {
        int r  = i >> 5;
        int c4 = (i & 31) << 2;
        int g  = row0 + r;
        float4 vx = make_float4(0.f, 0.f, 0.f, 0.f);
        float4 vn = make_float4(0.f, 0.f, 0.f, 0.f);
        if (g < nRows) {
            vx = *reinterpret_cast<const float4*>(xin   + (size_t)g * F + c4);
            vn = *reinterpret_cast<const float4*>(neigh + (size_t)g * F + c4);
        }
        *reinterpret_cast<float4*>(&As[r][c4]) = vx;
        *reinterpret_cast<float4*>(&An[r][c4]) = vn;
    }
    __syncthreads();

    const int cg = tid % CG;
    const int rg = tid / CG;
    const int c  = cg * 4;
    const int rb = rg * RPT;

    float acc[RPT][4];
#pragma unroll
    for (int r = 0; r < RPT; ++r)
        acc[r][0] = acc[r][1] = acc[r][2] = acc[r][3] = 0.f;

#pragma unroll 4
    for (int k = 0; k < F; ++k) {
        const float4 wsv = *reinterpret_cast<const float4*>(wself  + k * OUTF + c);
        const float4 wnv = *reinterpret_cast<const float4*>(wneigh + k * OUTF + c);
#pragma unroll
        for (int r = 0; r < RPT; ++r) {
            float ax = As[rb + r][k];
            float an = An[rb + r][k];
            acc[r][0] = fmaf(ax, wsv.x, fmaf(an, wnv.x, acc[r][0]));
            acc[r][1] = fmaf(ax, wsv.y, fmaf(an, wnv.y, acc[r][1]));
            acc[r][2] = fmaf(ax, wsv.z, fmaf(an, wnv.z, acc[r][2]));
            acc[r][3] = fmaf(ax, wsv.w, fmaf(an, wnv.w, acc[r][3]));
        }
    }

    const float4 bv = *reinterpret_cast<const float4*>(bias + c);
#pragma unroll
    for (int r = 0; r < RPT; ++r) {
        int g = row0 + rb + r;
        if (g >= nRows) continue;
        float4 o;
        o.x = acc[r][0] + bv.x;
        o.y = acc[r][1] + bv.y;
        o.z = acc[r][2] + bv.z;
        o.w = acc[r][3] + bv.w;
        if (RELU) {
            o.x = fmaxf(o.x, 0.f); o.y = fmaxf(o.y, 0.f);
            o.z = fmaxf(o.z, 0.f); o.w = fmaxf(o.w, 0.f);
        }
        *reinterpret_cast<float4*>(out + (size_t)g * OUTF + c) = o;
    }
}

extern "C" void kernel_launch(void* const* d_in, const int* in_sizes, int n_in,
                              void* d_out, int out_size, void* d_ws, size_t ws_size,
                              hipStream_t stream) {
    const float* x   = (const float*)d_in[0];
    const int*   src = (const int*)  d_in[1];
    const int*   dst = (const int*)  d_in[2];
    const float* ws1 = (const float*)d_in[3];
    const float* wn1 = (const float*)d_in[4];
    const float* b1  = (const float*)d_in[5];
    const float* ws2 = (const float*)d_in[6];
    const float* wn2 = (const float*)d_in[7];
    const float* b2  = (const float*)d_in[8];
    const float* ws3 = (const float*)d_in[9];
    const float* wn3 = (const float*)d_in[10];
    const float* b3  = (const float*)d_in[11];
    float* out = (float*)d_out;

    const int N = in_sizes[0] / F;   // 50000
    const int E = in_sizes[1];       // 640000

    // ---- workspace layout: cnt | rowptr | col | neigh | h ----
    char* w = (char*)d_ws;
    const size_t cntBytes  = ((size_t)N * 4 + 511) & ~(size_t)511;
    const size_t rpBytes   = ((size_t)(N + 1) * 4 + 511) & ~(size_t)511;
    const size_t colBytes  = ((size_t)E * 4 + 511) & ~(size_t)511;
    const size_t featBytes = (size_t)N * F * 4;
    int*   cnt    = (int*)(w);                       // histogram, then reused as fill counter
    int*   rowptr = (int*)(w + cntBytes);
    int*   col    = (int*)(w + cntBytes + rpBytes);
    float* neigh  = (float*)(w + cntBytes + rpBytes + colBytes);
    float* h      = (float*)(w + cntBytes + rpBytes + colBytes + featBytes);

    const dim3 blk(256);
    const int edgeGrid   = (E + 255) / 256;
    const int gatherGrid = (int)(((size_t)N * 32 + 255) / 256);
    const int gemmGrid   = (N + 63) / 64;

    // ---- build dst-CSR once (graph identical for all 3 layers) ----
    hipMemsetAsync(cnt, 0, (size_t)N * 4, stream);
    hist_kernel<<<edgeGrid, blk, 0, stream>>>(dst, cnt, E);
    scan_kernel<<<1, 1024, 0, stream>>>(cnt, rowptr, N);
    hipMemsetAsync(cnt, 0, (size_t)N * 4, stream);   // reuse as fill counters
    fill_kernel<<<edgeGrid, blk, 0, stream>>>(src, dst, rowptr, cnt, col, E);

    // ---- layer 1: x -> h ----
    gather_kernel<<<gatherGrid, blk, 0, stream>>>(x, rowptr, col, neigh, N);
    sage_gemm<128, true><<<gemmGrid, blk, 0, stream>>>(x, neigh, ws1, wn1, b1, h, N);

    // ---- layer 2: h -> h (in place: gather completes before GEMM; GEMM rows are block-private) ----
    gather_kernel<<<gatherGrid, blk, 0, stream>>>(h, rowptr, col, neigh, N);
    sage_gemm<128, true><<<gemmGrid, blk, 0, stream>>>(h, neigh, ws2, wn2, b2, h, N);

    // ---- layer 3: h -> out (64 cols, no relu) ----
    gather_kernel<<<gatherGrid, blk, 0, stream>>>(h, rowptr, col, neigh, N);
    sage_gemm<64, false><<<gemmGrid, blk, 0, stream>>>(h, neigh, ws3, wn3, b3, out, N);
}

// Round 3
// 375.955 us; speedup vs baseline: 9.1732x; 1.1985x over previous
//
#include <hip/hip_runtime.h>

static constexpr int F = 128;   // feature width of x / hidden layers

// ---------------- CSR build step 1: int histogram of dst ----------------
__global__ __launch_bounds__(256) void hist_kernel(const int* __restrict__ dst,
                                                   int* __restrict__ cnt, int nE) {
    int i = blockIdx.x * blockDim.x + threadIdx.x;
    if (i < nE) atomicAdd(&cnt[dst[i]], 1);
}

// ---------------- CSR build step 2a: per-block sums of cnt ----------------
__global__ __launch_bounds__(256) void scanA_kernel(const int* __restrict__ cnt,
                                                    int* __restrict__ bsums, int n) {
    __shared__ int s[256];
    const int tid = threadIdx.x;
    const int i = blockIdx.x * 256 + tid;
    s[tid] = (i < n) ? cnt[i] : 0;
    __syncthreads();
#pragma unroll
    for (int off = 128; off > 0; off >>= 1) {
        if (tid < off) s[tid] += s[tid + off];
        __syncthreads();
    }
    if (tid == 0) bsums[blockIdx.x] = s[0];
}

// ---------------- CSR build step 2b: exclusive scan of block sums (1 block) ----------------
__global__ __launch_bounds__(256) void scanB_kernel(int* __restrict__ bsums, int nb) {
    __shared__ int s[256];
    __shared__ int carry;
    const int tid = threadIdx.x;
    if (tid == 0) carry = 0;
    __syncthreads();
    for (int base = 0; base < nb; base += 256) {
        const int idx = base + tid;
        const int v = (idx < nb) ? bsums[idx] : 0;
        s[tid] = v;
        __syncthreads();
#pragma unroll
        for (int off = 1; off < 256; off <<= 1) {
            int t = (tid >= off) ? s[tid - off] : 0;
            __syncthreads();
            s[tid] += t;
            __syncthreads();
        }
        const int incl = s[tid] + carry;
        if (idx < nb) bsums[idx] = incl - v;   // exclusive
        __syncthreads();
        if (tid == 255) carry = incl;
        __syncthreads();
    }
}

// ---------------- CSR build step 2c: per-block inclusive scan + offset -> rowptr ----------------
__global__ __launch_bounds__(256) void scanC_kernel(const int* __restrict__ cnt,
                                                    const int* __restrict__ boff,
                                                    int* __restrict__ rowptr, int n) {
    __shared__ int s[256];
    const int tid = threadIdx.x;
    const int i = blockIdx.x * 256 + tid;
    const int v = (i < n) ? cnt[i] : 0;
    s[tid] = v;
    __syncthreads();
#pragma unroll
    for (int off = 1; off < 256; off <<= 1) {
        int t = (tid >= off) ? s[tid - off] : 0;
        __syncthreads();
        s[tid] += t;
        __syncthreads();
    }
    const int incl = s[tid] + boff[blockIdx.x];
    if (i < n) rowptr[i + 1] = incl;
    if (i == 0) rowptr[0] = 0;
}

// ---------------- CSR build step 3: bucket-fill src indices ----------------
__global__ __launch_bounds__(256) void fill_kernel(const int* __restrict__ src,
                                                   const int* __restrict__ dst,
                                                   const int* __restrict__ rowptr,
                                                   int* __restrict__ fillcnt,
                                                   int* __restrict__ col, int nE) {
    int e = blockIdx.x * blockDim.x + threadIdx.x;
    if (e < nE) {
        int d = dst[e];
        int pos = atomicAdd(&fillcnt[d], 1);
        col[rowptr[d] + pos] = src[e];
    }
}

// ---------------- gather: neigh[v] = mean_{u in N(v)} x[u]  (no atomics) ----------------
// 32 lanes per node, float4 per lane, 4-way unrolled neighbor loop for MLP.
__global__ __launch_bounds__(256) void gather_kernel(const float* __restrict__ x,
                                                     const int* __restrict__ rowptr,
                                                     const int* __restrict__ col,
                                                     float* __restrict__ neigh, int nNodes) {
    const int grp  = (blockIdx.x * blockDim.x + threadIdx.x) >> 5;
    const int lane = threadIdx.x & 31;
    if (grp >= nNodes) return;
    const int beg = rowptr[grp];
    const int end = rowptr[grp + 1];
    const int q   = lane << 2;

    float4 a0 = make_float4(0.f, 0.f, 0.f, 0.f);
    float4 a1 = make_float4(0.f, 0.f, 0.f, 0.f);
    float4 a2 = make_float4(0.f, 0.f, 0.f, 0.f);
    float4 a3 = make_float4(0.f, 0.f, 0.f, 0.f);

    int j = beg;
    for (; j + 3 < end; j += 4) {
        const int u0 = col[j], u1 = col[j + 1], u2 = col[j + 2], u3 = col[j + 3];
        const float4 v0 = *reinterpret_cast<const float4*>(x + (size_t)u0 * F + q);
        const float4 v1 = *reinterpret_cast<const float4*>(x + (size_t)u1 * F + q);
        const float4 v2 = *reinterpret_cast<const float4*>(x + (size_t)u2 * F + q);
        const float4 v3 = *reinterpret_cast<const float4*>(x + (size_t)u3 * F + q);
        a0.x += v0.x; a0.y += v0.y; a0.z += v0.z; a0.w += v0.w;
        a1.x += v1.x; a1.y += v1.y; a1.z += v1.z; a1.w += v1.w;
        a2.x += v2.x; a2.y += v2.y; a2.z += v2.z; a2.w += v2.w;
        a3.x += v3.x; a3.y += v3.y; a3.z += v3.z; a3.w += v3.w;
    }
    for (; j < end; ++j) {
        const int u = col[j];
        const float4 v = *reinterpret_cast<const float4*>(x + (size_t)u * F + q);
        a0.x += v.x; a0.y += v.y; a0.z += v.z; a0.w += v.w;
    }

    const int deg = end - beg;
    const float inv = 1.0f / (float)(deg > 1 ? deg : 1);
    float4 o;
    o.x = (a0.x + a1.x + a2.x + a3.x) * inv;
    o.y = (a0.y + a1.y + a2.y + a3.y) * inv;
    o.z = (a0.z + a1.z + a2.z + a3.z) * inv;
    o.w = (a0.w + a1.w + a2.w + a3.w) * inv;
    *reinterpret_cast<float4*>(neigh + (size_t)grp * F + q) = o;
}

// ---------------- fused SAGE layer GEMM ----------------
// out[r] = act( x[r] @ Wself + neigh[r] @ Wneigh + b )   (neigh pre-scaled by 1/deg)
// 256 threads/block, 64 rows/block, thread micro-tile = RPT rows x 4 cols.
// Inner loop steps k by 4 with ds_read_b128 row fragments (4x fewer LDS instrs).
template<int OUTF, bool RELU>
__global__ __launch_bounds__(256) void sage_gemm(const float* xin,
                                                 const float* __restrict__ neigh,
                                                 const float* __restrict__ wself,
                                                 const float* __restrict__ wneigh,
                                                 const float* __restrict__ bias,
                                                 float* out, int nRows)
{
    constexpr int MT  = 64;            // rows per block
    constexpr int CG  = OUTF / 4;      // col groups of 4
    constexpr int RPT = MT * CG / 256; // rows per thread (128->8, 64->4)
    __shared__ float As[MT][F];
    __shared__ float An[MT][F];

    const int tid  = threadIdx.x;
    const int row0 = blockIdx.x * MT;

    // ---- stage 64 rows of x and neigh into LDS (coalesced float4) ----
    for (int i = tid; i < MT * (F / 4); i += 256) {
        int r  = i >> 5;
        int c4 = (i & 31) << 2;
        int g  = row0 + r;
        float4 vx = make_float4(0.f, 0.f, 0.f, 0.f);
        float4 vn = make_float4(0.f, 0.f, 0.f, 0.f);
        if (g < nRows) {
            vx = *reinterpret_cast<const float4*>(xin   + (size_t)g * F + c4);
            vn = *reinterpret_cast<const float4*>(neigh + (size_t)g * F + c4);
        }
        *reinterpret_cast<float4*>(&As[r][c4]) = vx;
        *reinterpret_cast<float4*>(&An[r][c4]) = vn;
    }
    __syncthreads();

    const int cg = tid % CG;
    const int rg = tid / CG;
    const int c  = cg * 4;
    const int rb = rg * RPT;

    float acc[RPT][4];
#pragma unroll
    for (int r = 0; r < RPT; ++r)
        acc[r][0] = acc[r][1] = acc[r][2] = acc[r][3] = 0.f;

#pragma unroll 2
    for (int k = 0; k < F; k += 4) {
        float4 ws[4], wn[4];
#pragma unroll
        for (int kk = 0; kk < 4; ++kk) {
            ws[kk] = *reinterpret_cast<const float4*>(wself  + (k + kk) * OUTF + c);
            wn[kk] = *reinterpret_cast<const float4*>(wneigh + (k + kk) * OUTF + c);
        }
#pragma unroll
        for (int r = 0; r < RPT; ++r) {
            const float4 ax = *reinterpret_cast<const float4*>(&As[rb + r][k]);
            const float4 an = *reinterpret_cast<const float4*>(&An[rb + r][k]);
            acc[r][0] = fmaf(ax.x, ws[0].x, acc[r][0]); acc[r][0] = fmaf(an.x, wn[0].x, acc[r][0]);
            acc[r][1] = fmaf(ax.x, ws[0].y, acc[r][1]); acc[r][1] = fmaf(an.x, wn[0].y, acc[r][1]);
            acc[r][2] = fmaf(ax.x, ws[0].z, acc[r][2]); acc[r][2] = fmaf(an.x, wn[0].z, acc[r][2]);
            acc[r][3] = fmaf(ax.x, ws[0].w, acc[r][3]); acc[r][3] = fmaf(an.x, wn[0].w, acc[r][3]);

            acc[r][0] = fmaf(ax.y, ws[1].x, acc[r][0]); acc[r][0] = fmaf(an.y, wn[1].x, acc[r][0]);
            acc[r][1] = fmaf(ax.y, ws[1].y, acc[r][1]); acc[r][1] = fmaf(an.y, wn[1].y, acc[r][1]);
            acc[r][2] = fmaf(ax.y, ws[1].z, acc[r][2]); acc[r][2] = fmaf(an.y, wn[1].z, acc[r][2]);
            acc[r][3] = fmaf(ax.y, ws[1].w, acc[r][3]); acc[r][3] = fmaf(an.y, wn[1].w, acc[r][3]);

            acc[r][0] = fmaf(ax.z, ws[2].x, acc[r][0]); acc[r][0] = fmaf(an.z, wn[2].x, acc[r][0]);
            acc[r][1] = fmaf(ax.z, ws[2].y, acc[r][1]); acc[r][1] = fmaf(an.z, wn[2].y, acc[r][1]);
            acc[r][2] = fmaf(ax.z, ws[2].z, acc[r][2]); acc[r][2] = fmaf(an.z, wn[2].z, acc[r][2]);
            acc[r][3] = fmaf(ax.z, ws[2].w, acc[r][3]); acc[r][3] = fmaf(an.z, wn[2].w, acc[r][3]);

            acc[r][0] = fmaf(ax.w, ws[3].x, acc[r][0]); acc[r][0] = fmaf(an.w, wn[3].x, acc[r][0]);
            acc[r][1] = fmaf(ax.w, ws[3].y, acc[r][1]); acc[r][1] = fmaf(an.w, wn[3].y, acc[r][1]);
            acc[r][2] = fmaf(ax.w, ws[3].z, acc[r][2]); acc[r][2] = fmaf(an.w, wn[3].z, acc[r][2]);
            acc[r][3] = fmaf(ax.w, ws[3].w, acc[r][3]); acc[r][3] = fmaf(an.w, wn[3].w, acc[r][3]);
        }
    }

    const float4 bv = *reinterpret_cast<const float4*>(bias + c);
#pragma unroll
    for (int r = 0; r < RPT; ++r) {
        int g = row0 + rb + r;
        if (g >= nRows) continue;
        float4 o;
        o.x = acc[r][0] + bv.x;
        o.y = acc[r][1] + bv.y;
        o.z = acc[r][2] + bv.z;
        o.w = acc[r][3] + bv.w;
        if (RELU) {
            o.x = fmaxf(o.x, 0.f); o.y = fmaxf(o.y, 0.f);
            o.z = fmaxf(o.z, 0.f); o.w = fmaxf(o.w, 0.f);
        }
        *reinterpret_cast<float4*>(out + (size_t)g * OUTF + c) = o;
    }
}

extern "C" void kernel_launch(void* const* d_in, const int* in_sizes, int n_in,
                              void* d_out, int out_size, void* d_ws, size_t ws_size,
                              hipStream_t stream) {
    const float* x   = (const float*)d_in[0];
    const int*   src = (const int*)  d_in[1];
    const int*   dst = (const int*)  d_in[2];
    const float* ws1 = (const float*)d_in[3];
    const float* wn1 = (const float*)d_in[4];
    const float* b1  = (const float*)d_in[5];
    const float* ws2 = (const float*)d_in[6];
    const float* wn2 = (const float*)d_in[7];
    const float* b2  = (const float*)d_in[8];
    const float* ws3 = (const float*)d_in[9];
    const float* wn3 = (const float*)d_in[10];
    const float* b3  = (const float*)d_in[11];
    float* out = (float*)d_out;

    const int N = in_sizes[0] / F;   // 50000
    const int E = in_sizes[1];       // 640000

    const int nScanBlocks = (N + 255) / 256;   // 196

    // ---- workspace layout: cnt | bsums | rowptr | col | neigh | h ----
    char* w = (char*)d_ws;
    const size_t cntBytes  = ((size_t)N * 4 + 511) & ~(size_t)511;
    const size_t bsBytes   = ((size_t)nScanBlocks * 4 + 511) & ~(size_t)511;
    const size_t rpBytes   = ((size_t)(N + 1) * 4 + 511) & ~(size_t)511;
    const size_t colBytes  = ((size_t)E * 4 + 511) & ~(size_t)511;
    const size_t featBytes = (size_t)N * F * 4;
    int*   cnt    = (int*)(w);                       // histogram, then reused as fill counter
    int*   bsums  = (int*)(w + cntBytes);
    int*   rowptr = (int*)(w + cntBytes + bsBytes);
    int*   col    = (int*)(w + cntBytes + bsBytes + rpBytes);
    float* neigh  = (float*)(w + cntBytes + bsBytes + rpBytes + colBytes);
    float* h      = (float*)(w + cntBytes + bsBytes + rpBytes + colBytes + featBytes);

    const dim3 blk(256);
    const int edgeGrid   = (E + 255) / 256;
    const int gatherGrid = (int)(((size_t)N * 32 + 255) / 256);
    const int gemmGrid   = (N + 63) / 64;

    // ---- build dst-CSR once (graph identical for all 3 layers) ----
    hipMemsetAsync(cnt, 0, (size_t)N * 4, stream);
    hist_kernel<<<edgeGrid, blk, 0, stream>>>(dst, cnt, E);
    scanA_kernel<<<nScanBlocks, blk, 0, stream>>>(cnt, bsums, N);
    scanB_kernel<<<1, blk, 0, stream>>>(bsums, nScanBlocks);
    scanC_kernel<<<nScanBlocks, blk, 0, stream>>>(cnt, bsums, rowptr, N);
    hipMemsetAsync(cnt, 0, (size_t)N * 4, stream);   // reuse as fill counters
    fill_kernel<<<edgeGrid, blk, 0, stream>>>(src, dst, rowptr, cnt, col, E);

    // ---- layer 1: x -> h ----
    gather_kernel<<<gatherGrid, blk, 0, stream>>>(x, rowptr, col, neigh, N);
    sage_gemm<128, true><<<gemmGrid, blk, 0, stream>>>(x, neigh, ws1, wn1, b1, h, N);

    // ---- layer 2: h -> h (in place: gather completes before GEMM; GEMM rows are block-private) ----
    gather_kernel<<<gatherGrid, blk, 0, stream>>>(h, rowptr, col, neigh, N);
    sage_gemm<128, true><<<gemmGrid, blk, 0, stream>>>(h, neigh, ws2, wn2, b2, h, N);

    // ---- layer 3: h -> out (64 cols, no relu) ----
    gather_kernel<<<gatherGrid, blk, 0, stream>>>(h, rowptr, col, neigh, N);
    sage_gemm<64, false><<<gemmGrid, blk, 0, stream>>>(h, neigh, ws3, wn3, b3, out, N);
}